// Round 11
// baseline (230.390 us; speedup 1.0000x reference)
//
#include <hip/hip_runtime.h>
#include <hip/hip_bf16.h>

typedef __bf16 bf16x8 __attribute__((ext_vector_type(8)));
typedef __bf16 bf16x4 __attribute__((ext_vector_type(4)));
typedef float f32x4 __attribute__((ext_vector_type(4)));

#define KDIM 4096   // K = 128 blocks * 32
#define NDIM 4096   // N = 128 blocks * 32
#define NBJ  128    // output block-columns
#define KB   128    // input  block-rows

#define NB      7       // wT blocks staged in LDS per batch (17.9 KB)
#define BLK_LDS 2560    // 32 rows * 80 B (64 B data + 16 B pad) per block

// ---- prep: [0, nnz) w-transpose | last block: CSC build ---------------------
// The x->xb conversion pass is GONE: k_bsmm reads x directly and converts
// in-register (kills the 32 MB xb write + 32 MB HBM re-read + ~15 us of prep).
__global__ __launch_bounds__(256) void k_prep(
    const float* __restrict__ w,
    const int* __restrict__ idx_i, const int* __restrict__ idx_j,
    __bf16* __restrict__ wT,
    int* __restrict__ colptr, int* __restrict__ colinfo,
    int nnz) {
    __shared__ char smem[2176];
    int b = blockIdx.x, t = threadIdx.x;

    if (b < nnz) {
        // wT[n][c][k] = bf16(w[n][k][c])
        auto tile = (__bf16(*)[33])smem;
        int n = b;
        float4 v = ((const float4*)(w + (size_t)n * 1024))[t];
        int e = t * 4, k = e >> 5, c = e & 31;
        tile[k][c + 0] = (__bf16)v.x; tile[k][c + 1] = (__bf16)v.y;
        tile[k][c + 2] = (__bf16)v.z; tile[k][c + 3] = (__bf16)v.w;
        __syncthreads();
        int f = t * 4, cc = f >> 5, kk = f & 31;
        bf16x4 o;
        o[0] = tile[kk + 0][cc]; o[1] = tile[kk + 1][cc];
        o[2] = tile[kk + 2][cc]; o[3] = tile[kk + 3][cc];
        ((bf16x4*)(wT + (size_t)n * 1024))[t] = o;
    } else {
        // CSC build: colptr + packed (ib<<16)|n colinfo
        int* cnt = (int*)smem;          // [NBJ]
        int* cur = cnt + NBJ;           // [NBJ]
        if (t < NBJ) cnt[t] = 0;
        __syncthreads();
        for (int n = t; n < nnz; n += 256) atomicAdd(&cnt[idx_j[n]], 1);
        __syncthreads();
        int mycount = (t < NBJ) ? cnt[t] : 0;
        for (int off = 1; off < NBJ; off <<= 1) {
            int add = (t < NBJ && t >= off) ? cnt[t - off] : 0;
            __syncthreads();
            if (t < NBJ) cnt[t] += add;
            __syncthreads();
        }
        if (t < NBJ) {
            colptr[t + 1] = cnt[t];
            cur[t] = cnt[t] - mycount;
            if (t == 0) colptr[0] = 0;
        }
        __syncthreads();
        for (int n = t; n < nnz; n += 256) {
            int j = idx_j[n];
            int pos = atomicAdd(&cur[j], 1);
            colinfo[pos] = (idx_i[n] << 16) | n;
        }
    }
}

// ---- main kernel ------------------------------------------------------------
// R6 champion structure (32-row waves, NB=7 wT-in-LDS, rc-major XCD decode,
// nfo-once metadata) with the A-operand read DIRECTLY from x (fp32) and
// converted in-register to bf16.  rc-major walk keeps each XCD's 2 MB x-chunk
// L2-resident: first j pays HBM once, the other 127 j's hit L2 (~200 cy),
// covered by depth-2 fp32-stage rotation + TLP.  Register audit at
// __launch_bounds__(256,6) (cap ~84): 2x16 fp32 stage + 16 acc + ~20 misc.
struct FStage { float4 u0, v0, u1, v1; };   // 16 VGPRs: two 8-float rows

__device__ __forceinline__ bf16x8 cvt8(float4 u, float4 v) {
    bf16x8 o;
    o[0]=(__bf16)u.x; o[1]=(__bf16)u.y; o[2]=(__bf16)u.z; o[3]=(__bf16)u.w;
    o[4]=(__bf16)v.x; o[5]=(__bf16)v.y; o[6]=(__bf16)v.z; o[7]=(__bf16)v.w;
    return o;
}

#define MFMA4(A0, A1, B0, B1)                                                  \
    acc[0][0] = __builtin_amdgcn_mfma_f32_16x16x32_bf16(A0, B0, acc[0][0], 0, 0, 0); \
    acc[0][1] = __builtin_amdgcn_mfma_f32_16x16x32_bf16(A0, B1, acc[0][1], 0, 0, 0); \
    acc[1][0] = __builtin_amdgcn_mfma_f32_16x16x32_bf16(A1, B0, acc[1][0], 0, 0, 0); \
    acc[1][1] = __builtin_amdgcn_mfma_f32_16x16x32_bf16(A1, B1, acc[1][1], 0, 0, 0);

__global__ __launch_bounds__(256, 6) void k_bsmm(
    const float* __restrict__ x, const __bf16* __restrict__ wT,
    const int* __restrict__ colptr, const int* __restrict__ colinfo,
    float* __restrict__ y, int M) {
    __shared__ int nfo[64];
    __shared__ __attribute__((aligned(16))) char wbuf[NB * BLK_LDS];  // 17.9 KB

    int RCH = M >> 7;                     // 128-row chunks (4 waves x 32 rows)
    int l = blockIdx.x;
    int rc, j;
    if ((RCH & 7) == 0) {
        // XCD s (= l%8 round-robin) walks all 128 j of one 128-row chunk:
        // per-XCD x working set = 2 MB (L2-resident after first touch).
        int rps = RCH >> 3;
        int s = l & 7, u = l >> 3;
        rc = s * rps + (u >> 7);
        j  = u & (NBJ - 1);
    } else {
        rc = l % RCH; j = l / RCH;
    }
    int t = threadIdx.x;
    int lane = t & 63, wave = t >> 6;
    int quad = lane >> 4, l16 = lane & 15;
    int wrow = rc * 128 + wave * 32;

    int beg = colptr[j], end = colptr[j + 1];
    int cnt = end - beg;

    f32x4 acc[2][2] = {};

    const float* xr0 = x + (size_t)(wrow + l16) * KDIM + quad * 8;       // row l16
    const float* xr1 = xr0 + (size_t)16 * KDIM;                          // row l16+16
    const char*  wread = wbuf + l16 * 80 + quad * 16;

    if (cnt > 0 && cnt <= 64) {
        // ---- fast path: metadata once
        if (t < cnt) nfo[t] = colinfo[beg + t];
        __syncthreads();

        for (int bb0 = 0; bb0 < cnt; bb0 += NB) {
            int cb = cnt - bb0; if (cb > NB) cb = NB;
            if (bb0 > 0) __syncthreads();                      // wbuf reuse guard

            // stage cb wT blocks into LDS (coalesced 16B reads, padded writes)
            for (int c = t; c < cb * 128; c += 256) {
                int b = c >> 7, w16 = c & 127;
                int n = nfo[bb0 + b] & 0xFFFF;
                bf16x8 v = *(const bf16x8*)(wT + (size_t)n * 1024 + w16 * 8);
                *(bf16x8*)(wbuf + b * BLK_LDS + (w16 >> 2) * 80 + (w16 & 3) * 16) = v;
            }
            __syncthreads();

            auto fF = [&](int p) {
                int pp = p < cb ? p : cb - 1;
                int ib = nfo[bb0 + pp] >> 16;                  // uniform LDS read
                const float* p0 = xr0 + ib * 32;
                const float* p1 = xr1 + ib * 32;
                FStage s;
                s.u0 = ((const float4*)p0)[0]; s.v0 = ((const float4*)p0)[1];
                s.u1 = ((const float4*)p1)[0]; s.v1 = ((const float4*)p1)[1];
                return s;
            };
            FStage F0 = fF(0);
            FStage F1 = fF(1);
            for (int p = 0; p < cb; ++p) {
                bf16x8 a0 = cvt8(F0.u0, F0.v0);
                bf16x8 a1 = cvt8(F0.u1, F0.v1);
                const char* wp = wread + p * BLK_LDS;
                bf16x8 b0 = *(const bf16x8*)(wp);
                bf16x8 b1 = *(const bf16x8*)(wp + 16 * 80);
                MFMA4(a0, a1, b0, b1);
                F0 = F1; F1 = fF(p + 2);
            }
        }
    } else if (cnt > 64) {
        // ---- slow path (statistically unreachable at this density)
        for (int bb = beg; bb < end; bb += NB) {
            int cb = end - bb; if (cb > NB) cb = NB;
            if (bb > beg) __syncthreads();
            if (t < cb) nfo[t] = colinfo[bb + t];
            __syncthreads();
            for (int c = t; c < cb * 128; c += 256) {
                int b = c >> 7, w16 = c & 127;
                int n = nfo[b] & 0xFFFF;
                bf16x8 v = *(const bf16x8*)(wT + (size_t)n * 1024 + w16 * 8);
                *(bf16x8*)(wbuf + b * BLK_LDS + (w16 >> 2) * 80 + (w16 & 3) * 16) = v;
            }
            __syncthreads();
            auto fF = [&](int p) {
                int pp = p < cb ? p : cb - 1;
                int ib = nfo[pp] >> 16;
                const float* p0 = xr0 + ib * 32;
                const float* p1 = xr1 + ib * 32;
                FStage s;
                s.u0 = ((const float4*)p0)[0]; s.v0 = ((const float4*)p0)[1];
                s.u1 = ((const float4*)p1)[0]; s.v1 = ((const float4*)p1)[1];
                return s;
            };
            FStage F0 = fF(0);
            FStage F1 = fF(1);
            for (int p = 0; p < cb; ++p) {
                bf16x8 a0 = cvt8(F0.u0, F0.v0);
                bf16x8 a1 = cvt8(F0.u1, F0.v1);
                const char* wp = wread + p * BLK_LDS;
                bf16x8 b0 = *(const bf16x8*)(wp);
                bf16x8 b1 = *(const bf16x8*)(wp + 16 * 80);
                MFMA4(a0, a1, b0, b1);
                F0 = F1; F1 = fF(p + 2);
            }
        }
    }

    // C/D layout: row = quad*4 + reg, col = lane&15
    #pragma unroll
    for (int r = 0; r < 2; ++r)
        #pragma unroll
        for (int ch = 0; ch < 2; ++ch)
            #pragma unroll
            for (int reg = 0; reg < 4; ++reg) {
                int row = wrow + r * 16 + quad * 4 + reg;
                int col = j * 32 + ch * 16 + l16;
                y[(size_t)row * NDIM + col] = acc[r][ch][reg];
            }
}

// ---- fallback (no workspace): fp32 reads, convert in-kernel -----------------
__global__ __launch_bounds__(256) void k_bsmm_nows(
    const float* __restrict__ x, const float* __restrict__ w,
    const int* __restrict__ idx_i, const int* __restrict__ idx_j,
    float* __restrict__ y, int nnz) {
    __shared__ int list[256];
    __shared__ int listn;
    __shared__ __bf16 tw[32][40];
    int j = blockIdx.y;
    int tid = threadIdx.x;
    int lane = tid & 63, wave = tid >> 6;
    int quad = lane >> 4, l16 = lane & 15;
    int wrow = blockIdx.x * 256 + wave * 64;

    if (tid == 0) listn = 0;
    __syncthreads();
    for (int n = tid; n < nnz; n += 256)
        if (idx_j[n] == j) { int p = atomicAdd(&listn, 1); list[p & 255] = n; }
    __syncthreads();
    int cnt = listn;

    f32x4 acc[4][2] = {};
    for (int p = 0; p < cnt; ++p) {
        int n = list[p];
        int ib = idx_i[n];
        {
            float4 v = ((const float4*)(w + (size_t)n * 1024))[tid];
            int e = tid * 4, k = e >> 5, c = e & 31;
            tw[c + 0][k] = (__bf16)v.x; tw[c + 1][k] = (__bf16)v.y;
            tw[c + 2][k] = (__bf16)v.z; tw[c + 3][k] = (__bf16)v.w;
        }
        __syncthreads();
        bf16x8 a[4];
        #pragma unroll
        for (int r = 0; r < 4; ++r) {
            const float* xp = x + (size_t)(wrow + r * 16 + l16) * KDIM + ib * 32 + quad * 8;
            float4 u = *(const float4*)(xp);
            float4 v = *(const float4*)(xp + 4);
            a[r][0] = (__bf16)u.x; a[r][1] = (__bf16)u.y; a[r][2] = (__bf16)u.z; a[r][3] = (__bf16)u.w;
            a[r][4] = (__bf16)v.x; a[r][5] = (__bf16)v.y; a[r][6] = (__bf16)v.z; a[r][7] = (__bf16)v.w;
        }
        bf16x8 b0 = *(const bf16x8*)&tw[l16][quad * 8];
        bf16x8 b1 = *(const bf16x8*)&tw[l16 + 16][quad * 8];
        #pragma unroll
        for (int r = 0; r < 4; ++r) {
            acc[r][0] = __builtin_amdgcn_mfma_f32_16x16x32_bf16(a[r], b0, acc[r][0], 0, 0, 0);
            acc[r][1] = __builtin_amdgcn_mfma_f32_16x16x32_bf16(a[r], b1, acc[r][1], 0, 0, 0);
        }
        __syncthreads();
    }

    #pragma unroll
    for (int r = 0; r < 4; ++r)
        #pragma unroll
        for (int ch = 0; ch < 2; ++ch)
            #pragma unroll
            for (int reg = 0; reg < 4; ++reg) {
                int row = wrow + r * 16 + quad * 4 + reg;
                int col = j * 32 + ch * 16 + l16;
                y[(size_t)row * NDIM + col] = acc[r][ch][reg];
            }
}

extern "C" void kernel_launch(void* const* d_in, const int* in_sizes, int n_in,
                              void* d_out, int out_size, void* d_ws, size_t ws_size,
                              hipStream_t stream) {
    const float* x     = (const float*)d_in[0];
    const float* w     = (const float*)d_in[1];
    const int*   idx_i = (const int*)d_in[2];
    const int*   idx_j = (const int*)d_in[3];
    float*       y     = (float*)d_out;

    int nnz = in_sizes[2];
    int M   = in_sizes[0] / KDIM;                   // 4096

    size_t wt_bytes = (size_t)nnz * 1024 * 2;
    size_t need = wt_bytes + (size_t)(NBJ + 2 + nnz) * 4;

    if (ws_size >= need && (M & 255) == 0 && nnz < 65536) {
        __bf16* wT      = (__bf16*)d_ws;
        int*    colptr  = (int*)((char*)d_ws + wt_bytes);
        int*    colinfo = colptr + NBJ + 1;
        k_prep<<<nnz + 1, 256, 0, stream>>>(w, idx_i, idx_j,
                                            wT, colptr, colinfo, nnz);
        k_bsmm<<<(M / 128) * NBJ, 256, 0, stream>>>(x, wT, colptr, colinfo, y, M);
    } else {
        k_bsmm_nows<<<dim3(M / 256, NBJ), 256, 0, stream>>>(x, w, idx_i, idx_j, y, nnz);
    }
}